// Round 3
// baseline (620.102 us; speedup 1.0000x reference)
//
#include <hip/hip_runtime.h>
#include <math.h>

#define TOKS 16384
#define CDIM 128
#define NH 4
#define HD 32
#define HID 512
#define QSCALE 0.17677669529663687f
#define LEPS 1e-5f

typedef const float* fp;

// ---------------- k1: LN1 + QKV GEMM (16 tokens per block, 384 threads) ----------------
__global__ __launch_bounds__(384) void k1_ln_qkv(fp x, fp g, fp b, fp w, fp wb,
                                                 float* __restrict__ qkv) {
    __shared__ float xn[16 * 132];
    __shared__ float mu[16], rs[16];
    const int base = blockIdx.x * 16;
    const int tid = threadIdx.x;

    for (int idx = tid; idx < 2048; idx += 384) {
        int t = idx >> 7, c = idx & 127;
        xn[t * 132 + c] = x[(base + t) * CDIM + c];
    }
    __syncthreads();
    if (tid < 16) {
        float s = 0.f;
        for (int c = 0; c < 128; c++) s += xn[tid * 132 + c];
        float m = s * (1.f / 128.f);
        float v = 0.f;
        for (int c = 0; c < 128; c++) { float d = xn[tid * 132 + c] - m; v += d * d; }
        mu[tid] = m;
        rs[tid] = rsqrtf(v * (1.f / 128.f) + LEPS);
    }
    __syncthreads();
    for (int idx = tid; idx < 2048; idx += 384) {
        int t = idx >> 7, c = idx & 127;
        xn[t * 132 + c] = (xn[t * 132 + c] - mu[t]) * rs[t] * g[c] + b[c];
    }
    __syncthreads();

    const int j = tid;  // 384 columns
    float acc[16];
#pragma unroll
    for (int t = 0; t < 16; t++) acc[t] = 0.f;
    for (int c = 0; c < 128; c += 4) {
        float w0 = w[(c + 0) * 384 + j];
        float w1 = w[(c + 1) * 384 + j];
        float w2 = w[(c + 2) * 384 + j];
        float w3 = w[(c + 3) * 384 + j];
#pragma unroll
        for (int t = 0; t < 16; t++) {
            float4 xv = *(const float4*)&xn[t * 132 + c];
            acc[t] += xv.x * w0 + xv.y * w1 + xv.z * w2 + xv.w * w3;
        }
    }
    float bj = wb[j];
    float sc = (j < 128) ? QSCALE : 1.f;
#pragma unroll
    for (int t = 0; t < 16; t++)
        qkv[(base + t) * 384 + j] = (acc[t] + bj) * sc;
}

// ---------------- k2: LDS-tiled neighborhood attention ----------------
// block = 256 threads = 16x16 query tile for one (batch, head).
// Stage 22x22 K-window (62 KB, XOR-swizzled f32) -> scores -> overwrite with V -> PV.
__global__ __launch_bounds__(256) void k2_attn(const float* __restrict__ qkv, fp rpb,
                                               float* __restrict__ attn) {
    __shared__ float kv[484 * 32];   // 61.9 KB, K then V (two-phase), swizzled
    __shared__ float rpb_s[169];
    const int tile = blockIdx.x;          // 0..15
    const int h = blockIdx.y;             // 0..3
    const int bb = blockIdx.z;            // 0..3
    const int ty0 = (tile >> 2) * 16, tx0 = (tile & 3) * 16;
    const int ky0 = min(max(ty0 - 3, 0), 42);
    const int kx0 = min(max(tx0 - 3, 0), 42);
    const int tid = threadIdx.x;
    if (tid < 169) rpb_s[tid] = rpb[h * 169 + tid];

    const float* qbase = qkv + (size_t)(bb << 12) * 384;

    // my query
    const int qy = ty0 + (tid >> 4), qx = tx0 + (tid & 15);
    const int token = (bb << 12) + qy * 64 + qx;
    float q[32];
    {
        const float4* qp = (const float4*)(qkv + (size_t)token * 384 + h * HD);
#pragma unroll
        for (int i = 0; i < 8; i++) {
            float4 t = qp[i];
            q[4 * i] = t.x; q[4 * i + 1] = t.y; q[4 * i + 2] = t.z; q[4 * i + 3] = t.w;
        }
    }

    // ---- stage K: thread handles (pos = tid>>3, d4 = tid&7), 32 positions/sweep
    const int d4s = tid & 7;
    for (int p = tid >> 3; p < 484; p += 32) {
        int py = p / 22, px = p - py * 22;
        int row = (ky0 + py) * 64 + (kx0 + px);
        float4 val = *(const float4*)(qbase + (size_t)row * 384 + 128 + h * HD + d4s * 4);
        int swz = d4s ^ (p & 7);
        *(float4*)&kv[p * 32 + swz * 4] = val;
    }
    __syncthreads();

    // ---- scores
    const int gsy = min(max(qy - 3, 0), 57), gsx = min(max(qx - 3, 0), 57);
    const int ly = gsy - ky0, lx = gsx - kx0;
    const int r0 = (gsy - qy + 6) * 13 + (gsx - qx + 6);
    float sc[49];
#pragma unroll
    for (int dy = 0; dy < 7; dy++) {
        int prow = (ly + dy) * 22 + lx;
#pragma unroll
        for (int dx = 0; dx < 7; dx++) {
            int p = prow + dx;
            int base = p * 32, sw = p & 7;
            float s = 0.f;
#pragma unroll
            for (int d4 = 0; d4 < 8; d4++) {
                float4 kk = *(const float4*)&kv[base + ((d4 ^ sw) << 2)];
                s += q[4 * d4] * kk.x + q[4 * d4 + 1] * kk.y +
                     q[4 * d4 + 2] * kk.z + q[4 * d4 + 3] * kk.w;
            }
            sc[dy * 7 + dx] = s + rpb_s[r0 + dy * 13 + dx];
        }
    }
    __syncthreads();   // everyone done reading K

    // ---- stage V (overwrite kv)
    for (int p = tid >> 3; p < 484; p += 32) {
        int py = p / 22, px = p - py * 22;
        int row = (ky0 + py) * 64 + (kx0 + px);
        float4 val = *(const float4*)(qbase + (size_t)row * 384 + 256 + h * HD + d4s * 4);
        int swz = d4s ^ (p & 7);
        *(float4*)&kv[p * 32 + swz * 4] = val;
    }

    // ---- softmax (registers, overlaps V staging latency)
    float mx = sc[0];
#pragma unroll
    for (int l = 1; l < 49; l++) mx = fmaxf(mx, sc[l]);
    float sum = 0.f;
#pragma unroll
    for (int l = 0; l < 49; l++) { sc[l] = __expf(sc[l] - mx); sum += sc[l]; }
    float inv = 1.f / sum;
    __syncthreads();   // V staged

    // ---- PV
    float o[32];
#pragma unroll
    for (int i = 0; i < 32; i++) o[i] = 0.f;
#pragma unroll
    for (int dy = 0; dy < 7; dy++) {
        int prow = (ly + dy) * 22 + lx;
#pragma unroll
        for (int dx = 0; dx < 7; dx++) {
            int p = prow + dx;
            int base = p * 32, sw = p & 7;
            float pr = sc[dy * 7 + dx] * inv;
#pragma unroll
            for (int d4 = 0; d4 < 8; d4++) {
                float4 vv = *(const float4*)&kv[base + ((d4 ^ sw) << 2)];
                o[4 * d4] += pr * vv.x; o[4 * d4 + 1] += pr * vv.y;
                o[4 * d4 + 2] += pr * vv.z; o[4 * d4 + 3] += pr * vv.w;
            }
        }
    }
    float4* op = (float4*)(attn + (size_t)token * CDIM + h * HD);
#pragma unroll
    for (int i = 0; i < 8; i++)
        op[i] = make_float4(o[4 * i], o[4 * i + 1], o[4 * i + 2], o[4 * i + 3]);
}

// ---------------- k3: proj + residual + LN2 stats (8 tokens per block, 128 threads) ----------------
__global__ __launch_bounds__(128) void k3_proj(const float* __restrict__ attn, fp x, fp pw, fp pb,
                                               float* __restrict__ h, float* __restrict__ stats) {
    __shared__ float at[8 * 132];
    __shared__ float ht[8 * 132];
    const int base = blockIdx.x * 8;
    const int tid = threadIdx.x;  // 128
#pragma unroll
    for (int t = 0; t < 8; t++) at[t * 132 + tid] = attn[(base + t) * CDIM + tid];
    __syncthreads();
    float acc[8];
#pragma unroll
    for (int t = 0; t < 8; t++) acc[t] = 0.f;
    for (int c = 0; c < 128; c += 4) {
        float w0 = pw[(c + 0) * 128 + tid];
        float w1 = pw[(c + 1) * 128 + tid];
        float w2 = pw[(c + 2) * 128 + tid];
        float w3 = pw[(c + 3) * 128 + tid];
#pragma unroll
        for (int t = 0; t < 8; t++) {
            float4 av = *(const float4*)&at[t * 132 + c];
            acc[t] += av.x * w0 + av.y * w1 + av.z * w2 + av.w * w3;
        }
    }
    float bj = pb[tid];
#pragma unroll
    for (int t = 0; t < 8; t++) {
        float hv = x[(base + t) * CDIM + tid] + acc[t] + bj;
        ht[t * 132 + tid] = hv;
        h[(base + t) * CDIM + tid] = hv;
    }
    __syncthreads();
    if (tid < 8) {
        float s = 0.f;
        for (int c = 0; c < 128; c++) s += ht[tid * 132 + c];
        float m = s * (1.f / 128.f);
        float v = 0.f;
        for (int c = 0; c < 128; c++) { float d = ht[tid * 132 + c] - m; v += d * d; }
        stats[(base + tid) * 2] = m;
        stats[(base + tid) * 2 + 1] = rsqrtf(v * (1.f / 128.f) + LEPS);
    }
}

// ---------------- k4: LN2 + fc1 + GELU (8 tokens per block, 512 threads) ----------------
__global__ __launch_bounds__(512) void k4_fc1(const float* __restrict__ h, const float* __restrict__ stats,
                                              fp g, fp b, fp w1, fp b1, float* __restrict__ y1) {
    __shared__ float hn[8 * 132];
    const int base = blockIdx.x * 8;
    const int tid = threadIdx.x;  // 512
    for (int idx = tid; idx < 1024; idx += 512) {
        int t = idx >> 7, c = idx & 127;
        float m = stats[(base + t) * 2], r = stats[(base + t) * 2 + 1];
        hn[t * 132 + c] = (h[(base + t) * CDIM + c] - m) * r * g[c] + b[c];
    }
    __syncthreads();
    const int j = tid;  // 512 columns
    float acc[8];
#pragma unroll
    for (int t = 0; t < 8; t++) acc[t] = 0.f;
    for (int c = 0; c < 128; c += 4) {
        float w0 = w1[(c + 0) * HID + j];
        float w1v = w1[(c + 1) * HID + j];
        float w2 = w1[(c + 2) * HID + j];
        float w3 = w1[(c + 3) * HID + j];
#pragma unroll
        for (int t = 0; t < 8; t++) {
            float4 hv = *(const float4*)&hn[t * 132 + c];
            acc[t] += hv.x * w0 + hv.y * w1v + hv.z * w2 + hv.w * w3;
        }
    }
    float bj = b1[j];
#pragma unroll
    for (int t = 0; t < 8; t++) {
        float z = acc[t] + bj;
        float ge = 0.5f * z * (1.f + erff(z * 0.70710678118654752f));
        y1[(base + t) * HID + j] = ge;
    }
}

// ---------------- k5: fc2 + residual -> out (8 tokens per block, 128 threads) ----------------
__global__ __launch_bounds__(128) void k5_fc2(const float* __restrict__ y1, const float* __restrict__ h,
                                              fp w2, fp b2, float* __restrict__ out) {
    __shared__ float yt[8 * 516];
    const int base = blockIdx.x * 8;
    const int tid = threadIdx.x;  // 128
    for (int idx = tid; idx < 4096; idx += 128) {
        int t = idx >> 9, c = idx & 511;
        yt[t * 516 + c] = y1[(base + t) * HID + c];
    }
    __syncthreads();
    float acc[8];
#pragma unroll
    for (int t = 0; t < 8; t++) acc[t] = 0.f;
    for (int c = 0; c < 512; c += 4) {
        float w0 = w2[(c + 0) * 128 + tid];
        float w1 = w2[(c + 1) * 128 + tid];
        float w2v = w2[(c + 2) * 128 + tid];
        float w3 = w2[(c + 3) * 128 + tid];
#pragma unroll
        for (int t = 0; t < 8; t++) {
            float4 yv = *(const float4*)&yt[t * 516 + c];
            acc[t] += yv.x * w0 + yv.y * w1 + yv.z * w2v + yv.w * w3;
        }
    }
    float bj = b2[tid];
#pragma unroll
    for (int t = 0; t < 8; t++)
        out[(base + t) * CDIM + tid] = h[(base + t) * CDIM + tid] + acc[t] + bj;
}

extern "C" void kernel_launch(void* const* d_in, const int* in_sizes, int n_in,
                              void* d_out, int out_size, void* d_ws, size_t ws_size,
                              hipStream_t stream) {
    fp x      = (fp)d_in[0];
    fp ln1_g  = (fp)d_in[1];
    fp ln1_b  = (fp)d_in[2];
    fp qkv_w  = (fp)d_in[3];
    fp qkv_b  = (fp)d_in[4];
    fp rpb    = (fp)d_in[5];
    fp proj_w = (fp)d_in[6];
    fp proj_b = (fp)d_in[7];
    fp ln2_g  = (fp)d_in[8];
    fp ln2_b  = (fp)d_in[9];
    fp fc1_w  = (fp)d_in[10];
    fp fc1_b  = (fp)d_in[11];
    fp fc2_w  = (fp)d_in[12];
    fp fc2_b  = (fp)d_in[13];
    float* out = (float*)d_out;

    float* ws    = (float*)d_ws;
    float* h     = ws;                       // 16384*128
    float* stats = h + TOKS * CDIM;          // 16384*2
    float* qkv   = stats + TOKS * 2;         // 16384*384
    float* attn  = qkv + TOKS * 384;         // 16384*128
    float* y1    = qkv;                      // 16384*512 (aliases qkv+attn, dead by k4)

    k1_ln_qkv<<<TOKS / 16, 384, 0, stream>>>(x, ln1_g, ln1_b, qkv_w, qkv_b, qkv);
    k2_attn<<<dim3(16, NH, 4), 256, 0, stream>>>(qkv, rpb, attn);
    k3_proj<<<TOKS / 8, 128, 0, stream>>>(attn, x, proj_w, proj_b, h, stats);
    k4_fc1<<<TOKS / 8, 512, 0, stream>>>(h, stats, ln2_g, ln2_b, fc1_w, fc1_b, y1);
    k5_fc2<<<TOKS / 8, 128, 0, stream>>>(y1, h, fc2_w, fc2_b, out);
}

// Round 4
// 301.650 us; speedup vs baseline: 2.0557x; 2.0557x over previous
//
#include <hip/hip_runtime.h>
#include <math.h>

#define TOKS 16384
#define CDIM 128
#define NH 4
#define HD 32
#define HID 512
#define QSCALE 0.17677669529663687f
#define LEPS 1e-5f

typedef const float* fp;

// ---------------- k1: LN1 + QKV GEMM (16 tokens per block, 384 threads) ----------------
__global__ __launch_bounds__(384) void k1_ln_qkv(fp x, fp g, fp b, fp w, fp wb,
                                                 float* __restrict__ qkv) {
    __shared__ float xn[16 * 132];
    __shared__ float mu[16], rs[16];
    const int base = blockIdx.x * 16;
    const int tid = threadIdx.x;

    for (int idx = tid; idx < 2048; idx += 384) {
        int t = idx >> 7, c = idx & 127;
        xn[t * 132 + c] = x[(base + t) * CDIM + c];
    }
    __syncthreads();
    if (tid < 16) {
        float s = 0.f;
        for (int c = 0; c < 128; c++) s += xn[tid * 132 + c];
        float m = s * (1.f / 128.f);
        float v = 0.f;
        for (int c = 0; c < 128; c++) { float d = xn[tid * 132 + c] - m; v += d * d; }
        mu[tid] = m;
        rs[tid] = rsqrtf(v * (1.f / 128.f) + LEPS);
    }
    __syncthreads();
    for (int idx = tid; idx < 2048; idx += 384) {
        int t = idx >> 7, c = idx & 127;
        xn[t * 132 + c] = (xn[t * 132 + c] - mu[t]) * rs[t] * g[c] + b[c];
    }
    __syncthreads();

    const int j = tid;  // 384 columns
    float acc[16];
#pragma unroll
    for (int t = 0; t < 16; t++) acc[t] = 0.f;
    for (int c = 0; c < 128; c += 4) {
        float w0 = w[(c + 0) * 384 + j];
        float w1 = w[(c + 1) * 384 + j];
        float w2 = w[(c + 2) * 384 + j];
        float w3 = w[(c + 3) * 384 + j];
#pragma unroll
        for (int t = 0; t < 16; t++) {
            float4 xv = *(const float4*)&xn[t * 132 + c];
            acc[t] += xv.x * w0 + xv.y * w1 + xv.z * w2 + xv.w * w3;
        }
    }
    float bj = wb[j];
    float sc = (j < 128) ? QSCALE : 1.f;
#pragma unroll
    for (int t = 0; t < 16; t++)
        qkv[(base + t) * 384 + j] = (acc[t] + bj) * sc;
}

// ---------------- k2: neighborhood attention, 4 lanes per (token, head), 8 dims each ----
__global__ __launch_bounds__(256) void k2_attn(const float* __restrict__ qkv, fp rpb,
                                               float* __restrict__ attn) {
    const int gid = blockIdx.x * 256 + threadIdx.x;   // 262144
    const int d = gid & 3;                            // dim quarter: dims d*8..d*8+7
    const int head = (gid >> 2) & 3;
    const int token = gid >> 4;
    const int bb = token >> 12;
    const int y = (token >> 6) & 63;
    const int xx = token & 63;
    const int sy = min(max(y - 3, 0), 57);
    const int sx = min(max(xx - 3, 0), 57);

    const int doff = 128 + head * HD + d * 8;         // K offset within qkv row
    const float4* qp = (const float4*)(qkv + (size_t)token * 384 + head * HD + d * 8);
    float4 q0 = qp[0], q1 = qp[1];

    float sc[49];
    const float* rp = rpb + head * 169 + (sy - y + 6) * 13 + (sx - xx + 6);
    const int nbase = (bb << 12) + sy * 64 + sx;
#pragma unroll
    for (int dy = 0; dy < 7; dy++) {
#pragma unroll
        for (int dx = 0; dx < 7; dx++) {
            const float4* kp = (const float4*)(qkv + (size_t)(nbase + dy * 64 + dx) * 384 + doff);
            float4 k0 = kp[0], k1 = kp[1];
            float s = q0.x * k0.x + q0.y * k0.y + q0.z * k0.z + q0.w * k0.w +
                      q1.x * k1.x + q1.y * k1.y + q1.z * k1.z + q1.w * k1.w;
            s += __shfl_xor(s, 1);
            s += __shfl_xor(s, 2);
            sc[dy * 7 + dx] = s + rp[dy * 13 + dx];
        }
    }
    float mx = sc[0];
#pragma unroll
    for (int l = 1; l < 49; l++) mx = fmaxf(mx, sc[l]);
    float sum = 0.f;
#pragma unroll
    for (int l = 0; l < 49; l++) { sc[l] = __expf(sc[l] - mx); sum += sc[l]; }
    float inv = 1.f / sum;

    float4 o0 = make_float4(0.f, 0.f, 0.f, 0.f), o1 = o0;
#pragma unroll
    for (int dy = 0; dy < 7; dy++) {
#pragma unroll
        for (int dx = 0; dx < 7; dx++) {
            float p = sc[dy * 7 + dx] * inv;
            const float4* vp = (const float4*)(qkv + (size_t)(nbase + dy * 64 + dx) * 384 + doff + 128);
            float4 v0 = vp[0], v1 = vp[1];
            o0.x += p * v0.x; o0.y += p * v0.y; o0.z += p * v0.z; o0.w += p * v0.w;
            o1.x += p * v1.x; o1.y += p * v1.y; o1.z += p * v1.z; o1.w += p * v1.w;
        }
    }
    float4* op = (float4*)(attn + (size_t)token * CDIM + head * HD + d * 8);
    op[0] = o0;
    op[1] = o1;
}

// ---------------- k3: proj + residual + LN2 stats (8 tokens per block, 128 threads) ----------------
__global__ __launch_bounds__(128) void k3_proj(const float* __restrict__ attn, fp x, fp pw, fp pb,
                                               float* __restrict__ h, float* __restrict__ stats) {
    __shared__ float at[8 * 132];
    __shared__ float ht[8 * 132];
    const int base = blockIdx.x * 8;
    const int tid = threadIdx.x;  // 128
#pragma unroll
    for (int t = 0; t < 8; t++) at[t * 132 + tid] = attn[(base + t) * CDIM + tid];
    __syncthreads();
    float acc[8];
#pragma unroll
    for (int t = 0; t < 8; t++) acc[t] = 0.f;
    for (int c = 0; c < 128; c += 4) {
        float w0 = pw[(c + 0) * 128 + tid];
        float w1 = pw[(c + 1) * 128 + tid];
        float w2 = pw[(c + 2) * 128 + tid];
        float w3 = pw[(c + 3) * 128 + tid];
#pragma unroll
        for (int t = 0; t < 8; t++) {
            float4 av = *(const float4*)&at[t * 132 + c];
            acc[t] += av.x * w0 + av.y * w1 + av.z * w2 + av.w * w3;
        }
    }
    float bj = pb[tid];
#pragma unroll
    for (int t = 0; t < 8; t++) {
        float hv = x[(base + t) * CDIM + tid] + acc[t] + bj;
        ht[t * 132 + tid] = hv;
        h[(base + t) * CDIM + tid] = hv;
    }
    __syncthreads();
    if (tid < 8) {
        float s = 0.f;
        for (int c = 0; c < 128; c++) s += ht[tid * 132 + c];
        float m = s * (1.f / 128.f);
        float v = 0.f;
        for (int c = 0; c < 128; c++) { float d = ht[tid * 132 + c] - m; v += d * d; }
        stats[(base + tid) * 2] = m;
        stats[(base + tid) * 2 + 1] = rsqrtf(v * (1.f / 128.f) + LEPS);
    }
}

// ---------------- k4: LN2 + fc1 + GELU (8 tokens per block, 512 threads) ----------------
__global__ __launch_bounds__(512) void k4_fc1(const float* __restrict__ h, const float* __restrict__ stats,
                                              fp g, fp b, fp w1, fp b1, float* __restrict__ y1) {
    __shared__ float hn[8 * 132];
    const int base = blockIdx.x * 8;
    const int tid = threadIdx.x;  // 512
    for (int idx = tid; idx < 1024; idx += 512) {
        int t = idx >> 7, c = idx & 127;
        float m = stats[(base + t) * 2], r = stats[(base + t) * 2 + 1];
        hn[t * 132 + c] = (h[(base + t) * CDIM + c] - m) * r * g[c] + b[c];
    }
    __syncthreads();
    const int j = tid;  // 512 columns
    float acc[8];
#pragma unroll
    for (int t = 0; t < 8; t++) acc[t] = 0.f;
    for (int c = 0; c < 128; c += 4) {
        float w0 = w1[(c + 0) * HID + j];
        float w1v = w1[(c + 1) * HID + j];
        float w2 = w1[(c + 2) * HID + j];
        float w3 = w1[(c + 3) * HID + j];
#pragma unroll
        for (int t = 0; t < 8; t++) {
            float4 hv = *(const float4*)&hn[t * 132 + c];
            acc[t] += hv.x * w0 + hv.y * w1v + hv.z * w2 + hv.w * w3;
        }
    }
    float bj = b1[j];
#pragma unroll
    for (int t = 0; t < 8; t++) {
        float z = acc[t] + bj;
        float ge = 0.5f * z * (1.f + erff(z * 0.70710678118654752f));
        y1[(base + t) * HID + j] = ge;
    }
}

// ---------------- k5: fc2 + residual -> out (8 tokens per block, 128 threads) ----------------
__global__ __launch_bounds__(128) void k5_fc2(const float* __restrict__ y1, const float* __restrict__ h,
                                              fp w2, fp b2, float* __restrict__ out) {
    __shared__ float yt[8 * 516];
    const int base = blockIdx.x * 8;
    const int tid = threadIdx.x;  // 128
    for (int idx = tid; idx < 4096; idx += 128) {
        int t = idx >> 9, c = idx & 511;
        yt[t * 516 + c] = y1[(base + t) * HID + c];
    }
    __syncthreads();
    float acc[8];
#pragma unroll
    for (int t = 0; t < 8; t++) acc[t] = 0.f;
    for (int c = 0; c < 512; c += 4) {
        float w0 = w2[(c + 0) * 128 + tid];
        float w1 = w2[(c + 1) * 128 + tid];
        float w2v = w2[(c + 2) * 128 + tid];
        float w3 = w2[(c + 3) * 128 + tid];
#pragma unroll
        for (int t = 0; t < 8; t++) {
            float4 yv = *(const float4*)&yt[t * 516 + c];
            acc[t] += yv.x * w0 + yv.y * w1 + yv.z * w2v + yv.w * w3;
        }
    }
    float bj = b2[tid];
#pragma unroll
    for (int t = 0; t < 8; t++)
        out[(base + t) * CDIM + tid] = h[(base + t) * CDIM + tid] + acc[t] + bj;
}

extern "C" void kernel_launch(void* const* d_in, const int* in_sizes, int n_in,
                              void* d_out, int out_size, void* d_ws, size_t ws_size,
                              hipStream_t stream) {
    fp x      = (fp)d_in[0];
    fp ln1_g  = (fp)d_in[1];
    fp ln1_b  = (fp)d_in[2];
    fp qkv_w  = (fp)d_in[3];
    fp qkv_b  = (fp)d_in[4];
    fp rpb    = (fp)d_in[5];
    fp proj_w = (fp)d_in[6];
    fp proj_b = (fp)d_in[7];
    fp ln2_g  = (fp)d_in[8];
    fp ln2_b  = (fp)d_in[9];
    fp fc1_w  = (fp)d_in[10];
    fp fc1_b  = (fp)d_in[11];
    fp fc2_w  = (fp)d_in[12];
    fp fc2_b  = (fp)d_in[13];
    float* out = (float*)d_out;

    float* ws    = (float*)d_ws;
    float* h     = ws;                       // 16384*128
    float* stats = h + TOKS * CDIM;          // 16384*2
    float* qkv   = stats + TOKS * 2;         // 16384*384
    float* attn  = qkv + TOKS * 384;         // 16384*128
    float* y1    = qkv;                      // 16384*512 (aliases qkv+attn, dead by k4)

    k1_ln_qkv<<<TOKS / 16, 384, 0, stream>>>(x, ln1_g, ln1_b, qkv_w, qkv_b, qkv);
    k2_attn<<<TOKS * NH * 4 / 256, 256, 0, stream>>>(qkv, rpb, attn);
    k3_proj<<<TOKS / 8, 128, 0, stream>>>(attn, x, proj_w, proj_b, h, stats);
    k4_fc1<<<TOKS / 8, 512, 0, stream>>>(h, stats, ln2_g, ln2_b, fc1_w, fc1_b, y1);
    k5_fc2<<<TOKS / 8, 128, 0, stream>>>(y1, h, fc2_w, fc2_b, out);
}

// Round 6
// 181.812 us; speedup vs baseline: 3.4107x; 1.6591x over previous
//
#include <hip/hip_runtime.h>
#include <math.h>

#define TOKS 16384
#define CDIM 128
#define NH 4
#define HD 32
#define HID 512
#define QSCALE 0.17677669529663687f
#define LEPS 1e-5f

typedef const float* fp;
typedef __attribute__((ext_vector_type(8))) short bf16x8;
typedef __attribute__((ext_vector_type(4))) float f32x4;

__device__ inline unsigned int bfp2(float a, float b) {
    unsigned int ua = __float_as_uint(a); ua = (ua + 0x7FFFu + ((ua >> 16) & 1u)) >> 16;
    unsigned int ub = __float_as_uint(b); ub = (ub + 0x7FFFu + ((ub >> 16) & 1u)) >> 16;
    return ua | (ub << 16);
}

// ---------------- k0: LN1 row stats (mean, rstd) ----------------
__global__ __launch_bounds__(256) void k0_stats(fp x, float* __restrict__ stats1) {
    const int t = threadIdx.x;
    const int row = blockIdx.x * 8 + (t >> 5);
    const int l = t & 31;
    const float4 v = *(const float4*)(x + (size_t)row * CDIM + l * 4);
    float s = v.x + v.y + v.z + v.w;
    float q = v.x * v.x + v.y * v.y + v.z * v.z + v.w * v.w;
#pragma unroll
    for (int m = 16; m >= 1; m >>= 1) { s += __shfl_xor(s, m); q += __shfl_xor(q, m); }
    if (l == 0) {
        float mu = s * (1.f / 128.f);
        float var = q * (1.f / 128.f) - mu * mu;
        stats1[row * 2] = mu;
        stats1[row * 2 + 1] = rsqrtf(var + LEPS);
    }
}

// ================= MFMA GEMM kernels =================
// Tile: 64(M) x 64(N), 256 threads = 4 waves, each wave 16 rows x 4 n-tiles.
// LDS: A[64 rows][64 dwords] bf16 + Bt[64 n][64 dwords] bf16, 16B-chunk XOR swizzle.
// A/B frag: lane&15 = own index (m or n), k = quad*8 + j; D: row=quad*4+reg, col=lane&15.

// ---------------- k1: LN1-apply + QKV GEMM (K=128, N=384) ----------------
__global__ __launch_bounds__(256) void k1_mfma(fp x, fp stats1, fp g, fp b, fp w, fp wb,
                                               float* __restrict__ qkv) {
    __shared__ unsigned int lds[8192];
    const int m0 = blockIdx.x * 64;
    const int nb = blockIdx.y * 64;
    const int tid = threadIdx.x;
    // A stage (LN1 applied, f32->bf16): 2048 slots = 64 rows x 32 float4-chunks
#pragma unroll
    for (int i = 0; i < 8; i++) {
        int slot = tid + i * 256;
        int m = slot >> 5, f4 = slot & 31, k0 = f4 * 4;
        const float4 xv = *(const float4*)(x + (size_t)(m0 + m) * CDIM + k0);
        float mu = stats1[(m0 + m) * 2], rs = stats1[(m0 + m) * 2 + 1];
        const float4 gv = *(const float4*)(g + k0);
        const float4 bv = *(const float4*)(b + k0);
        float a0 = (xv.x - mu) * rs * gv.x + bv.x, a1 = (xv.y - mu) * rs * gv.y + bv.y;
        float a2 = (xv.z - mu) * rs * gv.z + bv.z, a3 = (xv.w - mu) * rs * gv.w + bv.w;
        unsigned int* p = &lds[m * 64 + ((f4 >> 1) ^ (m & 15)) * 4 + (f4 & 1) * 2];
        p[0] = bfp2(a0, a1); p[1] = bfp2(a2, a3);
    }
    // B stage (transpose to [n][k]): 4096 dwords
#pragma unroll
    for (int i = 0; i < 16; i++) {
        int idx = tid + i * 256;
        int n = idx & 63, kp = idx >> 6, k = kp * 2;
        float b0 = w[(size_t)k * 384 + nb + n];
        float b1v = w[(size_t)(k + 1) * 384 + nb + n];
        lds[4096 + n * 64 + ((k >> 3) ^ (n & 15)) * 4 + ((k >> 1) & 3)] = bfp2(b0, b1v);
    }
    __syncthreads();

    const int lane = tid & 63, wid = tid >> 6, quad = lane >> 4, l16 = lane & 15;
    const int mrow = wid * 16 + l16;
    f32x4 acc[4];
#pragma unroll
    for (int nt = 0; nt < 4; nt++) acc[nt] = (f32x4){0.f, 0.f, 0.f, 0.f};
#pragma unroll
    for (int kk = 0; kk < 128; kk += 32) {
        int c = (kk >> 3) + quad;
        bf16x8 a = *(bf16x8*)&lds[mrow * 64 + (c ^ l16) * 4];
#pragma unroll
        for (int nt = 0; nt < 4; nt++) {
            bf16x8 bf = *(bf16x8*)&lds[4096 + (nt * 16 + l16) * 64 + (c ^ l16) * 4];
            acc[nt] = __builtin_amdgcn_mfma_f32_16x16x32_bf16(a, bf, acc[nt], 0, 0, 0);
        }
    }
#pragma unroll
    for (int nt = 0; nt < 4; nt++) {
        int col = nb + nt * 16 + l16;
        float bias = wb[col];
        float sc = (col < 128) ? QSCALE : 1.f;
#pragma unroll
        for (int r = 0; r < 4; r++) {
            int row = m0 + wid * 16 + quad * 4 + r;
            qkv[(size_t)row * 384 + col] = (acc[nt][r] + bias) * sc;
        }
    }
}

// ---------------- k4: LN2-apply + fc1 + GELU (K=128, N=512) ----------------
__global__ __launch_bounds__(256) void k4_mfma(fp h, fp stats, fp g, fp b, fp w, fp wb,
                                               float* __restrict__ y1) {
    __shared__ unsigned int lds[8192];
    const int m0 = blockIdx.x * 64;
    const int nb = blockIdx.y * 64;
    const int tid = threadIdx.x;
#pragma unroll
    for (int i = 0; i < 8; i++) {
        int slot = tid + i * 256;
        int m = slot >> 5, f4 = slot & 31, k0 = f4 * 4;
        const float4 xv = *(const float4*)(h + (size_t)(m0 + m) * CDIM + k0);
        float mu = stats[(m0 + m) * 2], rs = stats[(m0 + m) * 2 + 1];
        const float4 gv = *(const float4*)(g + k0);
        const float4 bv = *(const float4*)(b + k0);
        float a0 = (xv.x - mu) * rs * gv.x + bv.x, a1 = (xv.y - mu) * rs * gv.y + bv.y;
        float a2 = (xv.z - mu) * rs * gv.z + bv.z, a3 = (xv.w - mu) * rs * gv.w + bv.w;
        unsigned int* p = &lds[m * 64 + ((f4 >> 1) ^ (m & 15)) * 4 + (f4 & 1) * 2];
        p[0] = bfp2(a0, a1); p[1] = bfp2(a2, a3);
    }
#pragma unroll
    for (int i = 0; i < 16; i++) {
        int idx = tid + i * 256;
        int n = idx & 63, kp = idx >> 6, k = kp * 2;
        float b0 = w[(size_t)k * HID + nb + n];
        float b1v = w[(size_t)(k + 1) * HID + nb + n];
        lds[4096 + n * 64 + ((k >> 3) ^ (n & 15)) * 4 + ((k >> 1) & 3)] = bfp2(b0, b1v);
    }
    __syncthreads();

    const int lane = tid & 63, wid = tid >> 6, quad = lane >> 4, l16 = lane & 15;
    const int mrow = wid * 16 + l16;
    f32x4 acc[4];
#pragma unroll
    for (int nt = 0; nt < 4; nt++) acc[nt] = (f32x4){0.f, 0.f, 0.f, 0.f};
#pragma unroll
    for (int kk = 0; kk < 128; kk += 32) {
        int c = (kk >> 3) + quad;
        bf16x8 a = *(bf16x8*)&lds[mrow * 64 + (c ^ l16) * 4];
#pragma unroll
        for (int nt = 0; nt < 4; nt++) {
            bf16x8 bf = *(bf16x8*)&lds[4096 + (nt * 16 + l16) * 64 + (c ^ l16) * 4];
            acc[nt] = __builtin_amdgcn_mfma_f32_16x16x32_bf16(a, bf, acc[nt], 0, 0, 0);
        }
    }
#pragma unroll
    for (int nt = 0; nt < 4; nt++) {
        int col = nb + nt * 16 + l16;
        float bias = wb[col];
#pragma unroll
        for (int r = 0; r < 4; r++) {
            int row = m0 + wid * 16 + quad * 4 + r;
            float z = acc[nt][r] + bias;
            y1[(size_t)row * HID + col] = 0.5f * z * (1.f + erff(z * 0.70710678118654752f));
        }
    }
}

// ---------------- k5: fc2 + residual (K=512 in 4 chunks, N=128) ----------------
__global__ __launch_bounds__(256) void k5_mfma(fp y1, fp h, fp w, fp wb,
                                               float* __restrict__ out) {
    __shared__ unsigned int lds[8192];
    const int m0 = blockIdx.x * 64;
    const int nb = blockIdx.y * 64;
    const int tid = threadIdx.x;
    const int lane = tid & 63, wid = tid >> 6, quad = lane >> 4, l16 = lane & 15;
    const int mrow = wid * 16 + l16;
    f32x4 acc[4];
#pragma unroll
    for (int nt = 0; nt < 4; nt++) acc[nt] = (f32x4){0.f, 0.f, 0.f, 0.f};

    for (int kc = 0; kc < 4; kc++) {
        if (kc) __syncthreads();
#pragma unroll
        for (int i = 0; i < 8; i++) {
            int slot = tid + i * 256;
            int m = slot >> 5, f4 = slot & 31, k0 = f4 * 4;
            const float4 xv = *(const float4*)(y1 + (size_t)(m0 + m) * HID + kc * 128 + k0);
            unsigned int* p = &lds[m * 64 + ((f4 >> 1) ^ (m & 15)) * 4 + (f4 & 1) * 2];
            p[0] = bfp2(xv.x, xv.y); p[1] = bfp2(xv.z, xv.w);
        }
#pragma unroll
        for (int i = 0; i < 16; i++) {
            int idx = tid + i * 256;
            int n = idx & 63, kp = idx >> 6, k = kp * 2;
            float b0 = w[(size_t)(kc * 128 + k) * CDIM + nb + n];
            float b1v = w[(size_t)(kc * 128 + k + 1) * CDIM + nb + n];
            lds[4096 + n * 64 + ((k >> 3) ^ (n & 15)) * 4 + ((k >> 1) & 3)] = bfp2(b0, b1v);
        }
        __syncthreads();
#pragma unroll
        for (int kk = 0; kk < 128; kk += 32) {
            int c = (kk >> 3) + quad;
            bf16x8 a = *(bf16x8*)&lds[mrow * 64 + (c ^ l16) * 4];
#pragma unroll
            for (int nt = 0; nt < 4; nt++) {
                bf16x8 bf = *(bf16x8*)&lds[4096 + (nt * 16 + l16) * 64 + (c ^ l16) * 4];
                acc[nt] = __builtin_amdgcn_mfma_f32_16x16x32_bf16(a, bf, acc[nt], 0, 0, 0);
            }
        }
    }
#pragma unroll
    for (int nt = 0; nt < 4; nt++) {
        int col = nb + nt * 16 + l16;
        float bias = wb[col];
#pragma unroll
        for (int r = 0; r < 4; r++) {
            int row = m0 + wid * 16 + quad * 4 + r;
            out[(size_t)row * CDIM + col] = h[(size_t)row * CDIM + col] + acc[nt][r] + bias;
        }
    }
}

// ---------------- k2: neighborhood attention, 4 lanes per (token, head), 8 dims each ----
__global__ __launch_bounds__(256) void k2_attn(const float* __restrict__ qkv, fp rpb,
                                               float* __restrict__ attn) {
    const int gid = blockIdx.x * 256 + threadIdx.x;   // 262144
    const int d = gid & 3;
    const int head = (gid >> 2) & 3;
    const int token = gid >> 4;
    const int bb = token >> 12;
    const int y = (token >> 6) & 63;
    const int xx = token & 63;
    const int sy = min(max(y - 3, 0), 57);
    const int sx = min(max(xx - 3, 0), 57);

    const int doff = 128 + head * HD + d * 8;
    const float4* qp = (const float4*)(qkv + (size_t)token * 384 + head * HD + d * 8);
    float4 q0 = qp[0], q1 = qp[1];

    float sc[49];
    const float* rp = rpb + head * 169 + (sy - y + 6) * 13 + (sx - xx + 6);
    const int nbase = (bb << 12) + sy * 64 + sx;
#pragma unroll
    for (int dy = 0; dy < 7; dy++) {
#pragma unroll
        for (int dx = 0; dx < 7; dx++) {
            const float4* kp = (const float4*)(qkv + (size_t)(nbase + dy * 64 + dx) * 384 + doff);
            float4 k0 = kp[0], k1 = kp[1];
            float s = q0.x * k0.x + q0.y * k0.y + q0.z * k0.z + q0.w * k0.w +
                      q1.x * k1.x + q1.y * k1.y + q1.z * k1.z + q1.w * k1.w;
            s += __shfl_xor(s, 1);
            s += __shfl_xor(s, 2);
            sc[dy * 7 + dx] = s + rp[dy * 13 + dx];
        }
    }
    float mx = sc[0];
#pragma unroll
    for (int l = 1; l < 49; l++) mx = fmaxf(mx, sc[l]);
    float sum = 0.f;
#pragma unroll
    for (int l = 0; l < 49; l++) { sc[l] = __expf(sc[l] - mx); sum += sc[l]; }
    float inv = 1.f / sum;

    float4 o0 = make_float4(0.f, 0.f, 0.f, 0.f), o1 = o0;
#pragma unroll
    for (int dy = 0; dy < 7; dy++) {
#pragma unroll
        for (int dx = 0; dx < 7; dx++) {
            float p = sc[dy * 7 + dx] * inv;
            const float4* vp = (const float4*)(qkv + (size_t)(nbase + dy * 64 + dx) * 384 + doff + 128);
            float4 v0 = vp[0], v1 = vp[1];
            o0.x += p * v0.x; o0.y += p * v0.y; o0.z += p * v0.z; o0.w += p * v0.w;
            o1.x += p * v1.x; o1.y += p * v1.y; o1.z += p * v1.z; o1.w += p * v1.w;
        }
    }
    float4* op = (float4*)(attn + (size_t)token * CDIM + head * HD + d * 8);
    op[0] = o0;
    op[1] = o1;
}

// ---------------- k3: proj + residual + LN2 stats (vector, unchanged) ----------------
__global__ __launch_bounds__(128) void k3_proj(const float* __restrict__ attn, fp x, fp pw, fp pb,
                                               float* __restrict__ h, float* __restrict__ stats) {
    __shared__ float at[8 * 132];
    __shared__ float ht[8 * 132];
    const int base = blockIdx.x * 8;
    const int tid = threadIdx.x;
#pragma unroll
    for (int t = 0; t < 8; t++) at[t * 132 + tid] = attn[(base + t) * CDIM + tid];
    __syncthreads();
    float acc[8];
#pragma unroll
    for (int t = 0; t < 8; t++) acc[t] = 0.f;
    for (int c = 0; c < 128; c += 4) {
        float w0 = pw[(c + 0) * 128 + tid];
        float w1 = pw[(c + 1) * 128 + tid];
        float w2 = pw[(c + 2) * 128 + tid];
        float w3 = pw[(c + 3) * 128 + tid];
#pragma unroll
        for (int t = 0; t < 8; t++) {
            float4 av = *(const float4*)&at[t * 132 + c];
            acc[t] += av.x * w0 + av.y * w1 + av.z * w2 + av.w * w3;
        }
    }
    float bj = pb[tid];
#pragma unroll
    for (int t = 0; t < 8; t++) {
        float hv = x[(base + t) * CDIM + tid] + acc[t] + bj;
        ht[t * 132 + tid] = hv;
        h[(base + t) * CDIM + tid] = hv;
    }
    __syncthreads();
    if (tid < 8) {
        float s = 0.f;
        for (int c = 0; c < 128; c++) s += ht[tid * 132 + c];
        float m = s * (1.f / 128.f);
        float v = 0.f;
        for (int c = 0; c < 128; c++) { float d = ht[tid * 132 + c] - m; v += d * d; }
        stats[(base + tid) * 2] = m;
        stats[(base + tid) * 2 + 1] = rsqrtf(v * (1.f / 128.f) + LEPS);
    }
}

extern "C" void kernel_launch(void* const* d_in, const int* in_sizes, int n_in,
                              void* d_out, int out_size, void* d_ws, size_t ws_size,
                              hipStream_t stream) {
    fp x      = (fp)d_in[0];
    fp ln1_g  = (fp)d_in[1];
    fp ln1_b  = (fp)d_in[2];
    fp qkv_w  = (fp)d_in[3];
    fp qkv_b  = (fp)d_in[4];
    fp rpb    = (fp)d_in[5];
    fp proj_w = (fp)d_in[6];
    fp proj_b = (fp)d_in[7];
    fp ln2_g  = (fp)d_in[8];
    fp ln2_b  = (fp)d_in[9];
    fp fc1_w  = (fp)d_in[10];
    fp fc1_b  = (fp)d_in[11];
    fp fc2_w  = (fp)d_in[12];
    fp fc2_b  = (fp)d_in[13];
    float* out = (float*)d_out;

    float* ws    = (float*)d_ws;
    float* h     = ws;                       // 16384*128
    float* stats = h + TOKS * CDIM;          // 16384*2   (LN2 stats, from k3)
    float* qkv   = stats + TOKS * 2;         // 16384*384
    float* attn  = qkv + TOKS * 384;         // 16384*128
    float* y1    = qkv;                      // 16384*512 (aliases qkv+attn, dead by k4)
    float* stats1 = attn;                    // 16384*2   (LN1 stats; attn region dead until k2)

    k0_stats<<<TOKS / 8, 256, 0, stream>>>(x, stats1);
    k1_mfma<<<dim3(TOKS / 64, 6), 256, 0, stream>>>(x, stats1, ln1_g, ln1_b, qkv_w, qkv_b, qkv);
    k2_attn<<<TOKS * NH * 4 / 256, 256, 0, stream>>>(qkv, rpb, attn);
    k3_proj<<<TOKS / 8, 128, 0, stream>>>(attn, x, proj_w, proj_b, h, stats);
    k4_mfma<<<dim3(TOKS / 64, 8), 256, 0, stream>>>(h, stats, ln2_g, ln2_b, fc1_w, fc1_b, y1);
    k5_mfma<<<dim3(TOKS / 64, 2), 256, 0, stream>>>(y1, h, fc2_w, fc2_b, out);
}